// Round 1
// baseline (77.362 us; speedup 1.0000x reference)
//
#include <hip/hip_runtime.h>
#include <math.h>

// Transfer-matrix closed form of the 22-qubit, 4-block RY+CNOT-ladder circuit.
//
// CNOT ladder C (q=0..20, control q, target q+1) maps basis |b> -> |Tb>,
// (Tb)_k = XOR_{j<=k} b_j; T^{-1} is the gray decode j_w = i_w ^ i_{w-1}.
// Amplitude A(i) = <i| C L3 C L2 C L1 C L0 |0>. Expanding each permutation
// with running-prefix bits (x,y,z) gives a bond-dim-8 matrix product:
//   A(i) = ones^T M_21(j_21) ... M_0(j_0) e_0,   j = i ^ (i>>1) (address space)
// M_w(jb)[(X'Y'Z'),(XYZ)] = R3_w(jb,X') R2_w(X^X',Y') R1_w(Y^Y',Z') f0_w(Z^Z')
// where Rb_w = RY(phi[b,w]) = [[c,-s],[s,c]], f0_w = column 0 of R0_w.
//
// Split at wire 10/11: Vpre[2048][8] (prefix, column vectors from e0) and
// Wsuf[8][2048] (suffix, row vectors from ones^T, SoA planes).
// out[i] = (Wsuf[J&2047] . Vpre[J>>11])^2,  J = i ^ (i>>1).

#define VPRE_OFF 0        // 2048*8 floats
#define WSUF_OFF 16384    // 8*2048 floats (SoA: plane r at WSUF_OFF + r*2048)
#define CS_OFF   32768    // c[4][22] then s[4][22] (176 floats)
// ws requirement: (32768 + 176) * 4 = 131,776 bytes

__device__ __forceinline__ float ry_el(float c, float s, int o, int i) {
  // RY matrix [[c,-s],[s,c]] element [out][in]
  return (o == 0) ? ((i == 0) ? c : -s) : ((i == 0) ? s : c);
}

__device__ __forceinline__ void build_M(const float* __restrict__ ws, int w, int jb,
                                        float* __restrict__ Mm) {
  const float c0 = ws[CS_OFF + w],      s0 = ws[CS_OFF + 88 + w];
  const float c1 = ws[CS_OFF + 22 + w], s1 = ws[CS_OFF + 88 + 22 + w];
  const float c2 = ws[CS_OFF + 44 + w], s2 = ws[CS_OFF + 88 + 44 + w];
  const float c3 = ws[CS_OFF + 66 + w], s3 = ws[CS_OFF + 88 + 66 + w];
  #pragma unroll
  for (int o = 0; o < 8; ++o) {
    const int Xp = (o >> 2) & 1, Yp = (o >> 1) & 1, Zp = o & 1;
    const float r3 = ry_el(c3, s3, jb, Xp);
    #pragma unroll
    for (int i = 0; i < 8; ++i) {
      const int X = (i >> 2) & 1, Y = (i >> 1) & 1, Z = i & 1;
      const float r2 = ry_el(c2, s2, X ^ Xp, Yp);
      const float r1 = ry_el(c1, s1, Y ^ Yp, Zp);
      const float f0 = ((Z ^ Zp) == 0) ? c0 : s0;
      Mm[o * 8 + i] = r3 * r2 * r1 * f0;
    }
  }
}

__global__ __launch_bounds__(256) void qc_build_tables(const float* __restrict__ phi,
                                                       float* __restrict__ ws) {
  __shared__ float bufA[8192];  // up to 1024 vectors of 8 floats
  __shared__ float bufB[8192];
  const int tid = threadIdx.x;

  // Phase 0: cos/sin table (both blocks write identical values; benign).
  if (tid < 88) {
    const float t = 0.5f * phi[tid];
    ws[CS_OFF + tid]      = cosf(t);
    ws[CS_OFF + 88 + tid] = sinf(t);
  }
  __threadfence();
  __syncthreads();

  float* cur = bufA;
  float* nxt = bufB;

  if (blockIdx.x == 0) {
    // ---- Vpre: v_w = M_w(j_w) v_{w-1}, v_{-1} = e0. Index t: new bit at bottom.
    if (tid == 0) {
      #pragma unroll
      for (int r = 0; r < 8; ++r) cur[r] = (r == 0) ? 1.0f : 0.0f;
    }
    __syncthreads();
    int size = 1;
    for (int w = 0; w <= 10; ++w) {
      const int jb = tid & 1;  // t = tid + 256k -> t&1 == tid&1
      float Mm[64];
      build_M(ws, w, jb, Mm);
      const int newsize = size << 1;
      for (int t = tid; t < newsize; t += 256) {
        const float* v = cur + (t >> 1) * 8;
        float inv[8], outv[8];
        #pragma unroll
        for (int i = 0; i < 8; ++i) inv[i] = v[i];
        #pragma unroll
        for (int o = 0; o < 8; ++o) {
          float acc = 0.0f;
          #pragma unroll
          for (int i = 0; i < 8; ++i) acc += Mm[o * 8 + i] * inv[i];
          outv[o] = acc;
        }
        if (w == 10) {
          #pragma unroll
          for (int o = 0; o < 8; ++o) ws[VPRE_OFF + t * 8 + o] = outv[o];
        } else {
          #pragma unroll
          for (int o = 0; o < 8; ++o) nxt[t * 8 + o] = outv[o];
        }
      }
      __syncthreads();
      float* tmp = cur; cur = nxt; nxt = tmp;
      size = newsize;
    }
  } else {
    // ---- Wsuf: W_w = W_{w+1} M_w(j_w), W_22 = ones^T. Index t: new bit at top (pos nb).
    if (tid == 0) {
      #pragma unroll
      for (int r = 0; r < 8; ++r) cur[r] = 1.0f;
    }
    __syncthreads();
    int size = 1;
    for (int w = 21; w >= 11; --w) {
      const int nb = 21 - w;
      const int newsize = size << 1;          // 2^(nb+1)
      const int C = (newsize > 256) ? (newsize >> 8) : 1;
      // chunked t = tid*C + k: bit nb of t is tid bit 7 when C>1, else tid bit nb
      const int jb = (newsize <= 256) ? ((tid >> nb) & 1) : ((tid >> 7) & 1);
      float Mm[64];
      build_M(ws, w, jb, Mm);
      for (int k = 0; k < C; ++k) {
        const int t = tid * C + k;
        if (t >= newsize) break;              // only possible when C==1
        const int tp = t & ((1 << nb) - 1);
        const float* v = cur + tp * 8;
        float inv[8], outv[8];
        #pragma unroll
        for (int i = 0; i < 8; ++i) inv[i] = v[i];
        #pragma unroll
        for (int i = 0; i < 8; ++i) {
          float acc = 0.0f;
          #pragma unroll
          for (int o = 0; o < 8; ++o) acc += inv[o] * Mm[o * 8 + i];
          outv[i] = acc;
        }
        if (w == 11) {
          #pragma unroll
          for (int i = 0; i < 8; ++i) ws[WSUF_OFF + i * 2048 + t] = outv[i];
        } else {
          #pragma unroll
          for (int i = 0; i < 8; ++i) nxt[t * 8 + i] = outv[i];
        }
      }
      __syncthreads();
      float* tmp = cur; cur = nxt; nxt = tmp;
      size = newsize;
    }
  }
}

__global__ __launch_bounds__(256) void qc_finalize(const float* __restrict__ ws,
                                                   float* __restrict__ out) {
  __shared__ float lw[16384];  // Wsuf SoA copy: [8][2048]
  const int tid = threadIdx.x;
  {
    const float4* src = (const float4*)(ws + WSUF_OFF);
    float4* dst = (float4*)lw;
    #pragma unroll
    for (int i = 0; i < 16; ++i) dst[tid + i * 256] = src[tid + i * 256];
  }
  __syncthreads();

  #pragma unroll
  for (int sg = 0; sg < 4; ++sg) {
    const unsigned seg  = blockIdx.x * 4u + sg;       // 512 blocks * 4 = 2048 segments
    const unsigned base = seg << 11;
    const unsigned p    = (base ^ (base >> 1)) >> 11; // uniform per segment
    const float* vp = ws + VPRE_OFF + p * 8;
    const float v0 = vp[0], v1 = vp[1], v2 = vp[2], v3 = vp[3];
    const float v4 = vp[4], v5 = vp[5], v6 = vp[6], v7 = vp[7];
    #pragma unroll
    for (int k = 0; k < 8; ++k) {
      const unsigned I = base + (unsigned)(k * 256) + tid;
      const unsigned J = I ^ (I >> 1);
      const unsigned s = J & 2047u;
      const float acc = lw[s]            * v0 + lw[2048 + s]     * v1
                      + lw[2 * 2048 + s] * v2 + lw[3 * 2048 + s] * v3
                      + lw[4 * 2048 + s] * v4 + lw[5 * 2048 + s] * v5
                      + lw[6 * 2048 + s] * v6 + lw[7 * 2048 + s] * v7;
      out[I] = acc * acc;
    }
  }
}

extern "C" void kernel_launch(void* const* d_in, const int* in_sizes, int n_in,
                              void* d_out, int out_size, void* d_ws, size_t ws_size,
                              hipStream_t stream) {
  (void)in_sizes; (void)n_in; (void)out_size; (void)ws_size;
  const float* phi = (const float*)d_in[0];  // (4,22) float32
  float* out = (float*)d_out;                // 2^22 float32 probs
  float* ws  = (float*)d_ws;                 // needs 131,776 bytes

  qc_build_tables<<<2, 256, 0, stream>>>(phi, ws);
  qc_finalize<<<512, 256, 0, stream>>>(ws, out);
}

// Round 2
// 65.265 us; speedup vs baseline: 1.1853x; 1.1853x over previous
//
#include <hip/hip_runtime.h>
#include <math.h>

// Transfer-matrix closed form of the 22-qubit, 4-block RY+CNOT-ladder circuit.
//
// CNOT ladder C (control q, target q+1, wire 0 = MSB) is the prefix-XOR
// permutation; its inverse in address space is gray decode J = I ^ (I>>1).
// Amplitude A(I) = ones^T M_21(j_21) ... M_0(j_0) e_0 with j_w = J bit (21-w),
// where M_w(jb) is a bond-dim-8 transfer matrix built from the 4 blocks'
// RY(phi[b,w]) rotations (running-prefix bits X,Y,Z of blocks 1..3):
//   M_w(jb)[(X'Y'Z'),(XYZ)] = R3(jb,X') R2(X^X',Y') R1(Y^Y',Z') f0(Z^Z')
//   Rb = [[c,-s],[s,c]] (c=cos(phi/2), s=sin(phi/2)), f0 = col 0 of R0.
//
// Split at wire 10/11: Vpre[2048][8] column vectors (wires 0..10 from e0),
// Wsuf[8][2048] row vectors SoA (wires 11..21 from ones^T).
// out[I] = (Wsuf[J & 2047] . Vpre[J >> 11])^2.
//
// Build: every table entry is an INDEPENDENT 11-step chain of factored
// 8x8 applies (~56 FLOP each) -> 4096 threads, no serialization.

#define VPRE_OFF 0        // 2048*8 floats
#define WSUF_OFF 16384    // 8*2048 floats (SoA plane r at WSUF_OFF + r*2048)
// ws requirement: 32768 * 4 = 131,072 bytes

// v' = M_w(jb) * v (column apply), factored into 4 stages.
__device__ __forceinline__ void apply_col(float v[8],
    float c0, float s0, float c1, float s1,
    float c2, float s2, float c3, float s3, int jb) {
  float a[8], b[8], t[8];
  // Z-stage: a(X,Y,Z') = sum_Z f0(Z^Z') v(X,Y,Z);  f0(0)=c0, f0(1)=s0
  #pragma unroll
  for (int xy = 0; xy < 4; ++xy) {
    const float v0 = v[xy * 2 + 0], v1 = v[xy * 2 + 1];
    a[xy * 2 + 0] = c0 * v0 + s0 * v1;
    a[xy * 2 + 1] = s0 * v0 + c0 * v1;
  }
  // Y-stage: b(X,Y',Z') = sum_Y R1[Y^Y'][Z'] a(X,Y,Z')
  #pragma unroll
  for (int X = 0; X < 2; ++X) {
    #pragma unroll
    for (int Zp = 0; Zp < 2; ++Zp) {
      const float a0 = a[X * 4 + 0 + Zp], a1 = a[X * 4 + 2 + Zp];
      const float r10 = Zp ? -s1 : c1;   // R1[0][Zp]
      const float r11 = Zp ?  c1 : s1;   // R1[1][Zp]
      b[X * 4 + 0 + Zp] = r10 * a0 + r11 * a1;
      b[X * 4 + 2 + Zp] = r11 * a0 + r10 * a1;
    }
  }
  // X-stage: t(X',Y',Z') = sum_X R2[X^X'][Y'] b(X,Y',Z')
  #pragma unroll
  for (int Yp = 0; Yp < 2; ++Yp) {
    #pragma unroll
    for (int Zp = 0; Zp < 2; ++Zp) {
      const float b0 = b[0 + Yp * 2 + Zp], b1 = b[4 + Yp * 2 + Zp];
      const float r20 = Yp ? -s2 : c2;   // R2[0][Yp]
      const float r21 = Yp ?  c2 : s2;   // R2[1][Yp]
      t[0 + Yp * 2 + Zp] = r20 * b0 + r21 * b1;
      t[4 + Yp * 2 + Zp] = r21 * b0 + r20 * b1;
    }
  }
  // R3 scale: v'(X',..) = R3[jb][X'] t(X',..)
  const float m0 = jb ? s3 : c3;    // R3[jb][0]
  const float m1 = jb ? c3 : -s3;   // R3[jb][1]
  #pragma unroll
  for (int yz = 0; yz < 4; ++yz) { v[yz] = m0 * t[yz]; v[4 + yz] = m1 * t[4 + yz]; }
}

// r' = r * M_w(jb) (row apply), factored into 4 stages.
__device__ __forceinline__ void apply_row(float r[8],
    float c0, float s0, float c1, float s1,
    float c2, float s2, float c3, float s3, int jb) {
  float g[8], h[8], k[8];
  const float m0 = jb ? s3 : c3;    // R3[jb][0]
  const float m1 = jb ? c3 : -s3;   // R3[jb][1]
  #pragma unroll
  for (int yz = 0; yz < 4; ++yz) { g[yz] = m0 * r[yz]; g[4 + yz] = m1 * r[4 + yz]; }
  // sum over X': h(X,Y',Z') = g(0,..)R2[X][Y'] + g(1,..)R2[X^1][Y']
  #pragma unroll
  for (int Yp = 0; Yp < 2; ++Yp) {
    #pragma unroll
    for (int Zp = 0; Zp < 2; ++Zp) {
      const float g0 = g[0 + Yp * 2 + Zp], g1 = g[4 + Yp * 2 + Zp];
      const float r20 = Yp ? -s2 : c2;   // R2[0][Yp]
      const float r21 = Yp ?  c2 : s2;   // R2[1][Yp]
      h[0 + Yp * 2 + Zp] = g0 * r20 + g1 * r21;   // X=0
      h[4 + Yp * 2 + Zp] = g0 * r21 + g1 * r20;   // X=1
    }
  }
  // sum over Y': k(X,Y,Z') = h(X,0,Z')R1[Y][Z'] + h(X,1,Z')R1[Y^1][Z']
  #pragma unroll
  for (int X = 0; X < 2; ++X) {
    #pragma unroll
    for (int Zp = 0; Zp < 2; ++Zp) {
      const float h0 = h[X * 4 + 0 + Zp], h1 = h[X * 4 + 2 + Zp];
      const float r10 = Zp ? -s1 : c1;
      const float r11 = Zp ?  c1 : s1;
      k[X * 4 + 0 + Zp] = h0 * r10 + h1 * r11;
      k[X * 4 + 2 + Zp] = h0 * r11 + h1 * r10;
    }
  }
  // sum over Z': r'(X,Y,Z) = k(..,0)f0(Z) + k(..,1)f0(Z^1)
  #pragma unroll
  for (int xy = 0; xy < 4; ++xy) {
    const float k0 = k[xy * 2 + 0], k1 = k[xy * 2 + 1];
    r[xy * 2 + 0] = k0 * c0 + k1 * s0;
    r[xy * 2 + 1] = k0 * s0 + k1 * c0;
  }
}

__global__ __launch_bounds__(256) void qc_build(const float* __restrict__ phi,
                                                float* __restrict__ ws) {
  __shared__ float cs[176];  // c[b*22+w], s at +88
  const int tid = threadIdx.x;
  if (tid < 88) {
    const float t = 0.5f * phi[tid];
    cs[tid]      = cosf(t);
    cs[88 + tid] = sinf(t);
  }
  __syncthreads();
  const int bid = blockIdx.x;
  if (bid < 8) {
    // Vpre entry t: j_w = bit (10-w) of t; apply M_0 .. M_10 to e0.
    const int t = bid * 256 + tid;
    float v[8] = {1.f, 0.f, 0.f, 0.f, 0.f, 0.f, 0.f, 0.f};
    #pragma unroll
    for (int w = 0; w <= 10; ++w) {
      const int jb = (t >> (10 - w)) & 1;
      apply_col(v, cs[w], cs[88 + w], cs[22 + w], cs[110 + w],
                cs[44 + w], cs[132 + w], cs[66 + w], cs[154 + w], jb);
    }
    #pragma unroll
    for (int o = 0; o < 8; ++o) ws[VPRE_OFF + t * 8 + o] = v[o];
  } else {
    // Wsuf entry t: j_w = bit (21-w) of t; r = ones^T M_21 ... M_11.
    const int t = (bid - 8) * 256 + tid;
    float r[8] = {1.f, 1.f, 1.f, 1.f, 1.f, 1.f, 1.f, 1.f};
    #pragma unroll
    for (int w = 21; w >= 11; --w) {
      const int jb = (t >> (21 - w)) & 1;
      apply_row(r, cs[w], cs[88 + w], cs[22 + w], cs[110 + w],
                cs[44 + w], cs[132 + w], cs[66 + w], cs[154 + w], jb);
    }
    #pragma unroll
    for (int i = 0; i < 8; ++i) ws[WSUF_OFF + i * 2048 + t] = r[i];
  }
}

__global__ __launch_bounds__(256) void qc_finalize(const float* __restrict__ ws,
                                                   float* __restrict__ out) {
  __shared__ float lw[16384];  // Wsuf SoA copy: [8][2048]
  const int tid = threadIdx.x;
  {
    const float4* src = (const float4*)(ws + WSUF_OFF);
    float4* dst = (float4*)lw;
    #pragma unroll
    for (int i = 0; i < 16; ++i) dst[tid + i * 256] = src[tid + i * 256];
  }
  __syncthreads();

  #pragma unroll
  for (int sg = 0; sg < 4; ++sg) {
    const unsigned seg  = blockIdx.x * 4u + sg;       // 512 blocks * 4 = 2048 segments
    const unsigned base = seg << 11;
    const unsigned p    = (base ^ (base >> 1)) >> 11; // uniform per segment
    const float* vp = ws + VPRE_OFF + p * 8;
    const float v0 = vp[0], v1 = vp[1], v2 = vp[2], v3 = vp[3];
    const float v4 = vp[4], v5 = vp[5], v6 = vp[6], v7 = vp[7];
    #pragma unroll
    for (int k = 0; k < 8; ++k) {
      const unsigned I = base + (unsigned)(k * 256) + tid;
      const unsigned J = I ^ (I >> 1);
      const unsigned s = J & 2047u;
      const float acc = lw[s]            * v0 + lw[2048 + s]     * v1
                      + lw[2 * 2048 + s] * v2 + lw[3 * 2048 + s] * v3
                      + lw[4 * 2048 + s] * v4 + lw[5 * 2048 + s] * v5
                      + lw[6 * 2048 + s] * v6 + lw[7 * 2048 + s] * v7;
      out[I] = acc * acc;
    }
  }
}

extern "C" void kernel_launch(void* const* d_in, const int* in_sizes, int n_in,
                              void* d_out, int out_size, void* d_ws, size_t ws_size,
                              hipStream_t stream) {
  (void)in_sizes; (void)n_in; (void)out_size; (void)ws_size;
  const float* phi = (const float*)d_in[0];  // (4,22) float32
  float* out = (float*)d_out;                // 2^22 float32 probs
  float* ws  = (float*)d_ws;                 // needs 131,072 bytes

  qc_build<<<16, 256, 0, stream>>>(phi, ws);
  qc_finalize<<<512, 256, 0, stream>>>(ws, out);
}

// Round 3
// 63.097 us; speedup vs baseline: 1.2261x; 1.0344x over previous
//
#include <hip/hip_runtime.h>
#include <math.h>

// Transfer-matrix closed form of the 22-qubit, 4-block RY+CNOT-ladder circuit.
//
// CNOT ladder C (control q, target q+1, wire 0 = MSB) is the prefix-XOR
// permutation; its inverse in address space is gray decode J = I ^ (I>>1).
// Amplitude A(I) = ones^T M_21(j_21) ... M_0(j_0) e_0 with j_w = J bit (21-w),
// where M_w(jb) is a bond-dim-8 transfer matrix built from the 4 blocks'
// RY(phi[b,w]) rotations (running-prefix bits X,Y,Z of blocks 1..3).
//
// Rank structure: out[I] = (Wsuf[s] . Vpre[p])^2 with J = I^(I>>1),
// s = J & 2047 (wires 11..21 from ones^T), p = J >> 11 (wires 0..10 from e0).
//
// This kernel inverts the map: thread owns a FIXED s (Wsuf[s] in 8 VGPRs,
// ~620-FLOP factored chain, recompute is cheap), iterates 32 block-uniform
// p values (Vpre via 1KB LDS broadcast), and stores to
//   I = (U11(p) << 11) | (U11(s) ^ (parity(p) ? 0x7FF : 0))
// where U11 = 11-bit inverse-gray (prefix-XOR). Per wave the 64 stores are a
// bijection of one aligned 256B window -> fully coalesced. No workspace use.

// v' = M_w(jb) * v (column apply), factored into 4 stages (~56 FLOP).
__device__ __forceinline__ void apply_col(float v[8],
    float c0, float s0, float c1, float s1,
    float c2, float s2, float c3, float s3, int jb) {
  float a[8], b[8], t[8];
  #pragma unroll
  for (int xy = 0; xy < 4; ++xy) {
    const float v0 = v[xy * 2 + 0], v1 = v[xy * 2 + 1];
    a[xy * 2 + 0] = c0 * v0 + s0 * v1;
    a[xy * 2 + 1] = s0 * v0 + c0 * v1;
  }
  #pragma unroll
  for (int X = 0; X < 2; ++X) {
    #pragma unroll
    for (int Zp = 0; Zp < 2; ++Zp) {
      const float a0 = a[X * 4 + 0 + Zp], a1 = a[X * 4 + 2 + Zp];
      const float r10 = Zp ? -s1 : c1;
      const float r11 = Zp ?  c1 : s1;
      b[X * 4 + 0 + Zp] = r10 * a0 + r11 * a1;
      b[X * 4 + 2 + Zp] = r11 * a0 + r10 * a1;
    }
  }
  #pragma unroll
  for (int Yp = 0; Yp < 2; ++Yp) {
    #pragma unroll
    for (int Zp = 0; Zp < 2; ++Zp) {
      const float b0 = b[0 + Yp * 2 + Zp], b1 = b[4 + Yp * 2 + Zp];
      const float r20 = Yp ? -s2 : c2;
      const float r21 = Yp ?  c2 : s2;
      t[0 + Yp * 2 + Zp] = r20 * b0 + r21 * b1;
      t[4 + Yp * 2 + Zp] = r21 * b0 + r20 * b1;
    }
  }
  const float m0 = jb ? s3 : c3;
  const float m1 = jb ? c3 : -s3;
  #pragma unroll
  for (int yz = 0; yz < 4; ++yz) { v[yz] = m0 * t[yz]; v[4 + yz] = m1 * t[4 + yz]; }
}

// r' = r * M_w(jb) (row apply), factored into 4 stages (~56 FLOP).
__device__ __forceinline__ void apply_row(float r[8],
    float c0, float s0, float c1, float s1,
    float c2, float s2, float c3, float s3, int jb) {
  float g[8], h[8], k[8];
  const float m0 = jb ? s3 : c3;
  const float m1 = jb ? c3 : -s3;
  #pragma unroll
  for (int yz = 0; yz < 4; ++yz) { g[yz] = m0 * r[yz]; g[4 + yz] = m1 * r[4 + yz]; }
  #pragma unroll
  for (int Yp = 0; Yp < 2; ++Yp) {
    #pragma unroll
    for (int Zp = 0; Zp < 2; ++Zp) {
      const float g0 = g[0 + Yp * 2 + Zp], g1 = g[4 + Yp * 2 + Zp];
      const float r20 = Yp ? -s2 : c2;
      const float r21 = Yp ?  c2 : s2;
      h[0 + Yp * 2 + Zp] = g0 * r20 + g1 * r21;
      h[4 + Yp * 2 + Zp] = g0 * r21 + g1 * r20;
    }
  }
  #pragma unroll
  for (int X = 0; X < 2; ++X) {
    #pragma unroll
    for (int Zp = 0; Zp < 2; ++Zp) {
      const float h0 = h[X * 4 + 0 + Zp], h1 = h[X * 4 + 2 + Zp];
      const float r10 = Zp ? -s1 : c1;
      const float r11 = Zp ?  c1 : s1;
      k[X * 4 + 0 + Zp] = h0 * r10 + h1 * r11;
      k[X * 4 + 2 + Zp] = h0 * r11 + h1 * r10;
    }
  }
  #pragma unroll
  for (int xy = 0; xy < 4; ++xy) {
    const float k0 = k[xy * 2 + 0], k1 = k[xy * 2 + 1];
    r[xy * 2 + 0] = k0 * c0 + k1 * s0;
    r[xy * 2 + 1] = k0 * s0 + k1 * c0;
  }
}

__global__ __launch_bounds__(256) void qc_fused(const float* __restrict__ phi,
                                                float* __restrict__ out) {
  __shared__ float cs[176];      // c[b*22+w], s at +88
  __shared__ float vp[32 * 8];   // this block's 32 Vpre vectors
  const int tid = threadIdx.x;
  if (tid < 88) {
    const float t = 0.5f * phi[tid];
    cs[tid]      = cosf(t);
    cs[88 + tid] = sinf(t);
  }
  __syncthreads();

  const unsigned b    = blockIdx.x;       // 512 blocks
  const unsigned sblk = b & 7u;           // s-window (8 x 256)
  const unsigned pblk = b >> 3;           // p-window (64 x 32)
  const unsigned s    = sblk * 256u + (unsigned)tid;
  const unsigned p0   = pblk * 32u;

  // Wsuf[s] = ones^T M_21 ... M_11  (row chain, jb = bit (21-w) of s)
  float r[8] = {1.f, 1.f, 1.f, 1.f, 1.f, 1.f, 1.f, 1.f};
  #pragma unroll
  for (int w = 21; w >= 11; --w) {
    const int jb = (int)((s >> (21 - w)) & 1u);
    apply_row(r, cs[w], cs[88 + w], cs[22 + w], cs[110 + w],
              cs[44 + w], cs[132 + w], cs[66 + w], cs[154 + w], jb);
  }

  // Vpre[p] = M_10 ... M_0 e0 (col chain, jb = bit (10-w) of p); all lanes
  // compute (8x redundant, no divergence), lanes 0..31 publish to LDS.
  {
    const unsigned p = p0 + ((unsigned)tid & 31u);
    float v[8] = {1.f, 0.f, 0.f, 0.f, 0.f, 0.f, 0.f, 0.f};
    #pragma unroll
    for (int w = 0; w <= 10; ++w) {
      const int jb = (int)((p >> (10 - w)) & 1u);
      apply_col(v, cs[w], cs[88 + w], cs[22 + w], cs[110 + w],
                cs[44 + w], cs[132 + w], cs[66 + w], cs[154 + w], jb);
    }
    if (tid < 32) {
      #pragma unroll
      for (int o = 0; o < 8; ++o) vp[tid * 8 + o] = v[o];
    }
  }
  __syncthreads();

  // U11(s): 11-bit inverse gray (prefix-XOR from MSB)
  unsigned us = s;
  us ^= us >> 1; us ^= us >> 2; us ^= us >> 4; us ^= us >> 8;
  us &= 2047u;

  #pragma unroll
  for (unsigned k = 0; k < 32; ++k) {
    const unsigned p = p0 + k;
    unsigned up = p;                      // U11(p), block-uniform -> SALU
    up ^= up >> 1; up ^= up >> 2; up ^= up >> 4; up ^= up >> 8;
    const unsigned ilow = us ^ ((0u - (up & 1u)) & 2047u);  // parity(p)=up&1
    const unsigned I = (up << 11) | ilow;
    const float4 va = reinterpret_cast<const float4*>(vp + k * 8)[0];
    const float4 vb = reinterpret_cast<const float4*>(vp + k * 8)[1];
    const float acc = r[0] * va.x + r[1] * va.y + r[2] * va.z + r[3] * va.w
                    + r[4] * vb.x + r[5] * vb.y + r[6] * vb.z + r[7] * vb.w;
    out[I] = acc * acc;
  }
}

extern "C" void kernel_launch(void* const* d_in, const int* in_sizes, int n_in,
                              void* d_out, int out_size, void* d_ws, size_t ws_size,
                              hipStream_t stream) {
  (void)in_sizes; (void)n_in; (void)out_size; (void)d_ws; (void)ws_size;
  const float* phi = (const float*)d_in[0];  // (4,22) float32
  float* out = (float*)d_out;                // 2^22 float32 probs

  qc_fused<<<512, 256, 0, stream>>>(phi, out);
}